// Round 2
// baseline (139.540 us; speedup 1.0000x reference)
//
#include <hip/hip_runtime.h>
#include <hip/hip_bf16.h>

#define B_     4
#define V_IN   12500
#define V_OUT  50000
#define C_IN   64
#define C_OUT  32
#define SPIRAL 9
#define K_NNZ  3
#define ROWS   (B_ * V_OUT)       // 200000
#define KDIM   (SPIRAL * C_IN)    // 576
#define KSTEPS (KDIM / 32)        // 18
#define NTILES (ROWS / 64)        // 3125
#define GRID2  1024               // gemm blocks; grid-stride over 3125 tiles
#define WFRAG_ELEMS (KSTEPS * 2 * 64 * 8)  // 18432 bf16 = 36864 B

typedef __attribute__((ext_vector_type(8))) short short8_t;   // 8 bf16 (4 VGPRs)
typedef __attribute__((ext_vector_type(4))) float floatx4;    // 4 fp32 acc

__device__ __forceinline__ unsigned short f32_to_bf16(float f) {
    unsigned int u = __float_as_uint(f);
    unsigned int r = u + 0x7fffu + ((u >> 16) & 1u);   // round-to-nearest-even
    return (unsigned short)(r >> 16);
}

// Kernel 1: up[b,v,c] = sum_k x[b, up_idx[v,k], c] * up_val[v,k]  -> bf16 in ws.
// blockIdx.x == ROWS/16: rearrange weight (576x32 fp32) into MFMA fragment
// order as bf16: w_frag[((kstep*2+ntile)*64 + lane)*8 + j]
//   = W[kstep*32 + (lane>>4)*8 + j][ntile*16 + (lane&15)]
// (element at lane position (p=lane&15, q=quad*8+j) == W[k][n] == W^T[n][k],
//  i.e. it serves as A-operand A[n][k] under the swapped-operand MFMA.)
__global__ __launch_bounds__(256) void upsample_kernel(
    const float* __restrict__ x,
    const int* __restrict__ up_idx,
    const float* __restrict__ up_val,
    const float* __restrict__ weight,
    unsigned short* __restrict__ up_bf16,
    unsigned short* __restrict__ w_frag)
{
    int tid = threadIdx.x;
    if (blockIdx.x == ROWS / 16) {
        for (int idx = tid; idx < WFRAG_ELEMS; idx += 256) {
            int j     = idx & 7;
            int lane  = (idx >> 3) & 63;
            int ntile = (idx >> 9) & 1;
            int kstep = idx >> 10;
            int k = kstep * 32 + (lane >> 4) * 8 + j;
            int n = ntile * 16 + (lane & 15);
            w_frag[idx] = f32_to_bf16(weight[k * C_OUT + n]);
        }
        return;
    }
    int r      = blockIdx.x * 16 + (tid >> 4);   // global row in [0, 200000)
    int lane16 = tid & 15;                       // 4 channels each
    int b = r / V_OUT;
    int v = r - b * V_OUT;
    const int*   ui = up_idx + v * K_NNZ;
    const float* uv = up_val + v * K_NNZ;
    float a0 = 0.f, a1 = 0.f, a2 = 0.f, a3 = 0.f;
#pragma unroll
    for (int k = 0; k < K_NNZ; k++) {
        int u = ui[k];
        float val = uv[k];
        const float4* xp = (const float4*)(x + ((size_t)b * V_IN + u) * C_IN) + lane16;
        float4 xv = *xp;
        a0 += val * xv.x; a1 += val * xv.y; a2 += val * xv.z; a3 += val * xv.w;
    }
    ushort4 o;
    o.x = f32_to_bf16(a0); o.y = f32_to_bf16(a1);
    o.z = f32_to_bf16(a2); o.w = f32_to_bf16(a3);
    *((ushort4*)(up_bf16 + (size_t)r * C_IN) + lane16) = o;
}

// Kernel 2: y[r, n] = relu( sum_f g[r,f] * W[f,n] + bias[n] ),
// g[r, s*64+c] = up[b, spiral[v,s], c].
// Swapped-operand MFMA: D = W^T-frag (as A) * g-frag (as B) = y^T tile,
// D[i=n', j=r'] with n' = quad*4+reg (+0/+16), r' = lane&15.
// Grid-stride over 64-row tiles; weights staged to LDS once per block.
__global__ __launch_bounds__(256) void gemm_kernel(
    const unsigned short* __restrict__ up_bf16,
    const int* __restrict__ spiral,
    const unsigned short* __restrict__ w_frag,
    const float* __restrict__ bias,
    float* __restrict__ out)
{
    __shared__ __align__(16) unsigned short w_lds[WFRAG_ELEMS];  // 36864 B
    int tid = threadIdx.x;
    {   // stage weight fragments to LDS once per block
        const uint4* src = (const uint4*)w_frag;
        uint4* dst = (uint4*)w_lds;
        for (int i = tid; i < WFRAG_ELEMS / 8; i += 256) dst[i] = src[i];
    }
    __syncthreads();

    int wave = tid >> 6;
    int lane = tid & 63;
    int m    = lane & 15;
    int quad = lane >> 4;

    float4 bias0 = ((const float4*)bias)[quad];      // bias[quad*4 .. +3]
    float4 bias1 = ((const float4*)bias)[4 + quad];  // bias[16+quad*4 .. +3]

    for (int tile = blockIdx.x; tile < NTILES; tile += GRID2) {
        int r = tile * 64 + wave * 16 + m;           // this lane's output row
        int b = r / V_OUT;
        int v = r - b * V_OUT;
        const int* sp = spiral + v * SPIRAL;
        size_t base = (size_t)b * V_OUT * C_IN;      // element offset into up

        // preload all 18 A(g)-fragments: maximizes outstanding loads
        short8_t g0[SPIRAL], g1[SPIRAL];
#pragma unroll
        for (int s = 0; s < SPIRAL; s++) {
            const unsigned short* rowp = up_bf16 + base + (size_t)sp[s] * C_IN;
            g0[s] = *(const short8_t*)(rowp + quad * 8);        // k-halves of the
            g1[s] = *(const short8_t*)(rowp + 32 + quad * 8);   // 64-ch segment
        }

        floatx4 acc0 = {0.f, 0.f, 0.f, 0.f};
        floatx4 acc1 = {0.f, 0.f, 0.f, 0.f};
#pragma unroll
        for (int kstep = 0; kstep < KSTEPS; kstep++) {
            short8_t gf = (kstep & 1) ? g1[kstep >> 1] : g0[kstep >> 1];
            const short8_t* wp0 = (const short8_t*)(w_lds + ((kstep * 2 + 0) * 64 + lane) * 8);
            const short8_t* wp1 = (const short8_t*)(w_lds + ((kstep * 2 + 1) * 64 + lane) * 8);
            acc0 = __builtin_amdgcn_mfma_f32_16x16x32_bf16(*wp0, gf, acc0, 0, 0, 0);
            acc1 = __builtin_amdgcn_mfma_f32_16x16x32_bf16(*wp1, gf, acc1, 0, 0, 0);
        }

        // epilogue: lane holds y[r][quad*4 .. +3] and y[r][16+quad*4 .. +3]
        float4 o0, o1;
        o0.x = acc0[0] + bias0.x; o0.y = acc0[1] + bias0.y;
        o0.z = acc0[2] + bias0.z; o0.w = acc0[3] + bias0.w;
        o1.x = acc1[0] + bias1.x; o1.y = acc1[1] + bias1.y;
        o1.z = acc1[2] + bias1.z; o1.w = acc1[3] + bias1.w;
        o0.x = o0.x > 0.f ? o0.x : 0.f;  o0.y = o0.y > 0.f ? o0.y : 0.f;
        o0.z = o0.z > 0.f ? o0.z : 0.f;  o0.w = o0.w > 0.f ? o0.w : 0.f;
        o1.x = o1.x > 0.f ? o1.x : 0.f;  o1.y = o1.y > 0.f ? o1.y : 0.f;
        o1.z = o1.z > 0.f ? o1.z : 0.f;  o1.w = o1.w > 0.f ? o1.w : 0.f;
        float* op = out + (size_t)r * C_OUT;
        *(float4*)(op + quad * 4)      = o0;
        *(float4*)(op + 16 + quad * 4) = o1;
    }
}

extern "C" void kernel_launch(void* const* d_in, const int* in_sizes, int n_in,
                              void* d_out, int out_size, void* d_ws, size_t ws_size,
                              hipStream_t stream) {
    const float* x      = (const float*)d_in[0];
    const int*   spiral = (const int*)d_in[1];
    const int*   up_idx = (const int*)d_in[2];
    const float* up_val = (const float*)d_in[3];
    const float* weight = (const float*)d_in[4];
    const float* bias   = (const float*)d_in[5];
    float* out = (float*)d_out;

    unsigned short* up_ws  = (unsigned short*)d_ws;          // 200000*64 bf16 = 25.6 MB
    unsigned short* w_frag = up_ws + (size_t)ROWS * C_IN;    // + 36864 B

    upsample_kernel<<<ROWS / 16 + 1, 256, 0, stream>>>(x, up_idx, up_val, weight, up_ws, w_frag);
    gemm_kernel<<<GRID2, 256, 0, stream>>>(up_ws, spiral, w_frag, bias, out);
}